// Round 5
// baseline (156.870 us; speedup 1.0000x reference)
//
#include <hip/hip_runtime.h>
#include <hip/hip_bf16.h>

// Problem constants
#define VOCAB 50000
#define ED    300
#define NT    16
#define BB    64
#define SS    512

#define LOG2E 1.4426950408889634f
#define LN2   0.6931471805599453f
#define WSTR  308   // padded W-transpose stride (2-way bank aliasing = free)

// ---------------------------------------------------------------------------
// Kernel 1: probs[row,:] = emb[text[row]] @ W + bias.  (verified, unchanged)
// ---------------------------------------------------------------------------
__global__ __launch_bounds__(256) void probs_kernel(const int* __restrict__ text,
                                                    const float* __restrict__ emb,
                                                    const float* __restrict__ W,
                                                    const float* __restrict__ bias,
                                                    float* __restrict__ out_probs) {
  __shared__ float wt[NT * WSTR];  // wt[t*WSTR + d] = W[d*16 + t]

  const int tid = threadIdx.x;
  const int lane = tid & 63, wave = tid >> 6;
  const int r = lane >> 4, t = lane & 15;
  const int row = blockIdx.x * 16 + wave * 4 + r;

  for (int e = tid; e < ED * NT; e += 256) {
    int d = e >> 4, tt = e & 15;
    wt[tt * WSTR + d] = W[e];
  }

  const int tok = text[row];
  const float4* erow = (const float4*)(emb + (size_t)tok * ED);
  float acc = bias[t];

  float4 A[8];
#pragma unroll
  for (int i = 0; i < 8; ++i) A[i] = erow[i];

  __syncthreads();

  const float4* w4 = (const float4*)(wt + t * WSTR);
#pragma unroll
  for (int c = 0; c < 75; ++c) {
    float4 e = A[c & 7];
    if (c < 67) A[c & 7] = erow[c + 8];
    float4 w = w4[c];
    acc = fmaf(e.x, w.x, acc);
    acc = fmaf(e.y, w.y, acc);
    acc = fmaf(e.z, w.z, acc);
    acc = fmaf(e.w, w.w, acc);
  }
  out_probs[(size_t)row * NT + t] = acc;
}

// ---------------------------------------------------------------------------
// DPP helpers (controls HW-verified).
// ---------------------------------------------------------------------------
template <int CTRL>
__device__ __forceinline__ float dppmov(float x) {
  int xi = __float_as_int(x);
  return __int_as_float(
      __builtin_amdgcn_update_dpp(xi, xi, CTRL, 0xF, 0xF, false));
}

// 16-lane max reduce (verified pattern)
__device__ __forceinline__ float max16(float x) {
  x = fmaxf(x, dppmov<0xB1>(x));
  x = fmaxf(x, dppmov<0x4E>(x));
  x = fmaxf(x, dppmov<0x141>(x));
  x = fmaxf(x, dppmov<0x140>(x));
  return x;
}

// ---------------------------------------------------------------------------
// One CRF step / matvec, fused DPP (HW-verified).
//   gn_j = (sum_m g_{j^m} * E[m]_j) * pe_j
// Each 16-lane group computes an independent matvec.
// ---------------------------------------------------------------------------
__device__ __forceinline__ float crf_step(float g, float pe, const float E[16]) {
  float gn, h, m, c, a1, a2, a3;
  asm("s_nop 1\n\t"
      "v_mov_b32_dpp %[h], %[g] row_half_mirror row_mask:0xf bank_mask:0xf\n\t"
      "v_mov_b32_dpp %[m], %[g] row_mirror row_mask:0xf bank_mask:0xf\n\t"
      "v_mul_f32 %[gn], %[g], %[e0]\n\t"
      "v_fmac_f32_dpp %[gn], %[g], %[e1] quad_perm:[1,0,3,2] row_mask:0xf bank_mask:0xf\n\t"
      "v_fmac_f32_dpp %[gn], %[g], %[e2] quad_perm:[2,3,0,1] row_mask:0xf bank_mask:0xf\n\t"
      "v_fmac_f32_dpp %[gn], %[g], %[e3] quad_perm:[3,2,1,0] row_mask:0xf bank_mask:0xf\n\t"
      "v_mov_b32_dpp %[c], %[m] row_half_mirror row_mask:0xf bank_mask:0xf\n\t"
      "v_mul_f32 %[a1], %[h], %[e7]\n\t"
      "v_fmac_f32_dpp %[a1], %[h], %[e6] quad_perm:[1,0,3,2] row_mask:0xf bank_mask:0xf\n\t"
      "v_fmac_f32_dpp %[a1], %[h], %[e5] quad_perm:[2,3,0,1] row_mask:0xf bank_mask:0xf\n\t"
      "v_fmac_f32_dpp %[a1], %[h], %[e4] quad_perm:[3,2,1,0] row_mask:0xf bank_mask:0xf\n\t"
      "v_mul_f32 %[a2], %[m], %[e15]\n\t"
      "v_fmac_f32_dpp %[a2], %[m], %[e14] quad_perm:[1,0,3,2] row_mask:0xf bank_mask:0xf\n\t"
      "v_fmac_f32_dpp %[a2], %[m], %[e13] quad_perm:[2,3,0,1] row_mask:0xf bank_mask:0xf\n\t"
      "v_fmac_f32_dpp %[a2], %[m], %[e12] quad_perm:[3,2,1,0] row_mask:0xf bank_mask:0xf\n\t"
      "v_mul_f32 %[a3], %[c], %[e8]\n\t"
      "v_fmac_f32_dpp %[a3], %[c], %[e9] quad_perm:[1,0,3,2] row_mask:0xf bank_mask:0xf\n\t"
      "v_fmac_f32_dpp %[a3], %[c], %[e10] quad_perm:[2,3,0,1] row_mask:0xf bank_mask:0xf\n\t"
      "v_fmac_f32_dpp %[a3], %[c], %[e11] quad_perm:[3,2,1,0] row_mask:0xf bank_mask:0xf\n\t"
      "v_add_f32 %[gn], %[gn], %[a1]\n\t"
      "v_add_f32 %[a2], %[a2], %[a3]\n\t"
      "v_add_f32 %[gn], %[gn], %[a2]\n\t"
      "v_mul_f32 %[gn], %[gn], %[pe]"
      : [gn] "=&v"(gn), [h] "=&v"(h), [m] "=&v"(m), [c] "=&v"(c),
        [a1] "=&v"(a1), [a2] "=&v"(a2), [a3] "=&v"(a3)
      : [g] "v"(g), [pe] "v"(pe),
        [e0] "v"(E[0]), [e1] "v"(E[1]), [e2] "v"(E[2]), [e3] "v"(E[3]),
        [e4] "v"(E[4]), [e5] "v"(E[5]), [e6] "v"(E[6]), [e7] "v"(E[7]),
        [e8] "v"(E[8]), [e9] "v"(E[9]), [e10] "v"(E[10]), [e11] "v"(E[11]),
        [e12] "v"(E[12]), [e13] "v"(E[13]), [e14] "v"(E[14]), [e15] "v"(E[15]));
  return gn;
}

// ---------------------------------------------------------------------------
// Phase A+B fused: per-segment 16x16 transfer-matrix products, then the
// LAST-FINISHING block of each batch (elected by a one-shot ACQ_REL
// fetch_add -- no polling, no spin; see rounds 1-2 post-mortems) runs the
// combine + scores tail. Numerics are op-for-op identical to the round-4
// passing pair (seg_kernel + crf2_kernel).
// Grid: 64 batches x 4 blocks, 256 threads (4 waves). Wave w of quarter q4
// owns segment seg = q4*4 + w (32 steps; prefix-active iff s < len; inactive
// steps leave exact unit columns -> identity).
// gm[(b*16+seg)*256 + m*16 + j] = P[j][j^m] (xor layout), scl = log2(max P).
// ---------------------------------------------------------------------------
__global__ __launch_bounds__(256) void seg_kernel(const int* __restrict__ text,
                                                  const int* __restrict__ tags,
                                                  const float* __restrict__ trans,
                                                  const float* __restrict__ probs,
                                                  float* __restrict__ gm,
                                                  float* __restrict__ scl,
                                                  int* __restrict__ cnt,
                                                  float* __restrict__ out_lens,
                                                  float* __restrict__ out_ll) {
  __shared__ float pe_lds[128 * 16];   // pe for this block's 128 rows
  __shared__ float xsc[4][16 * 17];    // per-wave transpose scratch (padded)
  __shared__ float hand[2];            // [0]=sc (wave1), [1]=log_norm (wave0)
  __shared__ int islast;

  const int tid = threadIdx.x;
  const int lane = tid & 63;
  const int w = tid >> 6;        // wave 0..3
  const int q = lane >> 4;       // lane group 0..3
  const int j = lane & 15;       // row index
  const int b = blockIdx.x >> 2;
  const int q4 = blockIdx.x & 3;
  const int seg = q4 * 4 + w;    // 0..15
  const int s_start = 1 + 32 * seg;
  const int segsz = (seg == 15) ? 31 : 32;

  // ---- stage pe = exp(probs) for rows [1+128*q4, 1+128*q4+128) ----
  {
    const float4* src = (const float4*)(probs + (size_t)b * SS * NT + (1 + 128 * q4) * NT);
    float4* dst = (float4*)pe_lds;
#pragma unroll
    for (int i = 0; i < 2; ++i) {
      float4 v = src[tid + 256 * i];
      v.x = exp2f(v.x * LOG2E);
      v.y = exp2f(v.y * LOG2E);
      v.z = exp2f(v.z * LOG2E);
      v.w = exp2f(v.w * LOG2E);
      dst[tid + 256 * i] = v;
    }
  }

  // ---- len (per-wave, verified pattern; redundant across waves) ----
  const int* tx = text + b * SS;
  int cz = 0;
#pragma unroll
  for (int k = 0; k < 8; ++k) cz += (tx[lane + 64 * k] != 0) ? 1 : 0;
  for (int off = 32; off > 0; off >>= 1) cz += __shfl_xor(cz, off, 64);
  const int len = cz;

  // ---- E[k] = exp(trans[j^k, j]) * 2^-5 ----
  float E[16];
#pragma unroll
  for (int k = 0; k < 16; ++k) E[k] = __expf(trans[((j ^ k) << 4) + j]) * 0.03125f;

  __syncthreads();  // pe_lds ready

  // ---- unit-column init: column c = 4q + r ----
  float g0 = (j == 4 * q + 0) ? 1.f : 0.f;
  float g1 = (j == 4 * q + 1) ? 1.f : 0.f;
  float g2 = (j == 4 * q + 2) ? 1.f : 0.f;
  float g3 = (j == 4 * q + 3) ? 1.f : 0.f;

  // ---- segment product: na active steps ----
  int na = len - s_start;
  na = (na < 0) ? 0 : ((na > segsz) ? segsz : na);

  const int row0 = 32 * w;
  for (int it = 0; it < na; ++it) {
    float pe = pe_lds[(row0 + it) * NT + j];
    g0 = crf_step(g0, pe, E);
    g1 = crf_step(g1, pe, E);
    g2 = crf_step(g2, pe, E);
    g3 = crf_step(g3, pe, E);
  }

  // ---- renorm matrix to max 1 (exact fold via scl) ----
  float mx = fmaxf(fmaxf(g0, g1), fmaxf(g2, g3));
  mx = max16(mx);
  mx = fmaxf(mx, __shfl_xor(mx, 16, 64));
  mx = fmaxf(mx, __shfl_xor(mx, 32, 64));
  float rr = 1.0f / mx;
  g0 *= rr; g1 *= rr; g2 *= rr; g3 *= rr;

  // ---- transpose to xor layout via per-wave LDS scratch ----
  float* xs = xsc[w];
  xs[(4 * q + 0) * 17 + j] = g0;   // xs[c*17 + row] = P[row][c]
  xs[(4 * q + 1) * 17 + j] = g1;
  xs[(4 * q + 2) * 17 + j] = g2;
  xs[(4 * q + 3) * 17 + j] = g3;
  // same-wave LDS write->read: lgkmcnt-ordered, no barrier needed
  float* outm = gm + ((size_t)(b * 16 + seg)) * 256;
#pragma unroll
  for (int r = 0; r < 4; ++r) {
    const int m = 4 * q + r;                 // group q emits m = 4q..4q+3
    outm[m * 16 + j] = xs[(j ^ m) * 17 + j]; // = P[j][j^m]
  }
  if (lane == 0) scl[b * 16 + seg] = __log2f(mx);

  // ---- last-block election (one-shot RMW; no polling) ----
  __syncthreads();  // drains each wave's vmcnt -> all gm/scl stores issued+done
  if (tid == 0) {
    __threadfence();  // release: write back this block's stores to coherent pt
    int old = __hip_atomic_fetch_add(&cnt[b * 16], 1, __ATOMIC_ACQ_REL,
                                     __HIP_MEMORY_SCOPE_AGENT);
    islast = (old == 3) ? 1 : 0;
  }
  __syncthreads();
  if (!islast) return;        // uniform per block; last block keeps all 4 waves
  __threadfence();            // acquire for every tail thread before gm reads

  // ======================= tail (one block per batch) ======================
  const float* pb = probs + (size_t)b * SS * NT;

  if (w == 0) {
    // ---- combine: alpha0 + 16 matvecs (round-4 crf2, verbatim) ----
    float K2 = 0.f;
#pragma unroll
    for (int k = 0; k < 16; ++k) K2 += scl[b * 16 + k];

    const float* gb = gm + (size_t)b * 16 * 256;
    float g = exp2f(pb[j] * LOG2E);

    float EA[16], EB[16];
#pragma unroll
    for (int m = 0; m < 16; ++m) EA[m] = gb[m * 16 + j];

    for (int k = 0; k < 16; k += 2) {
#pragma unroll
      for (int m = 0; m < 16; ++m) EB[m] = gb[(k + 1) * 256 + m * 16 + j];
      g = crf_step(g, 1.0f, EA);
      {
        float mxv = max16(g);
        float rv = 1.0f / mxv;
        K2 -= __log2f(rv);
        g *= rv;
      }
      if (k < 14) {
#pragma unroll
        for (int m = 0; m < 16; ++m) EA[m] = gb[(k + 2) * 256 + m * 16 + j];
      }
      g = crf_step(g, 1.0f, EB);
      {
        float mxv = max16(g);
        float rv = 1.0f / mxv;
        K2 -= __log2f(rv);
        g *= rv;
      }
    }

    const int T = (len > 0) ? len - 1 : 0;
    float x = g;
    x += dppmov<0xB1>(x);
    x += dppmov<0x4E>(x);
    x += dppmov<0x141>(x);
    x += dppmov<0x140>(x);
    float log_norm = LN2 * (K2 + 5.0f * (float)T + __log2f(x));
    if (lane == 0) hand[1] = log_norm;
  } else if (w == 1) {
    // ---- scores: lens out + binary + unary (round-4 crf2 numerics) ----
    if (lane == 0) out_lens[b] = (float)len;
    const int* tg = tags + b * SS;
    float sb = 0.f, su = 0.f;
#pragma unroll
    for (int it = 0; it < 8; ++it) {
      const int s = lane + 64 * it;
      int t1 = tg[s];
      if (s < len) {
        su += pb[s * NT + t1];
        if (s >= 1) sb += trans[tg[s - 1] * 16 + t1];
      }
    }
    float sc = su + sb;
    for (int off = 32; off > 0; off >>= 1) sc += __shfl_xor(sc, off, 64);
    if (lane == 0) hand[0] = sc;
  }

  __syncthreads();
  if (tid == 0) out_ll[b] = hand[0] - hand[1];
}

// ---------------------------------------------------------------------------
extern "C" void kernel_launch(void* const* d_in, const int* in_sizes, int n_in,
                              void* d_out, int out_size, void* d_ws, size_t ws_size,
                              hipStream_t stream) {
  const int* text = (const int*)d_in[0];
  const int* tags = (const int*)d_in[1];
  const float* emb = (const float*)d_in[2];
  const float* W = (const float*)d_in[3];
  const float* bias = (const float*)d_in[4];
  const float* trans = (const float*)d_in[5];

  float* out = (float*)d_out;
  float* out_probs = out;                   // 64*512*16
  float* out_lens = out + BB * SS * NT;     // 64
  float* out_ll = out + BB * SS * NT + BB;  // 64

  float* gm = (float*)d_ws;                 // 64*16*256 floats = 1 MB
  float* scl = gm + BB * 16 * 256;          // 64*16 floats
  int* cnt = (int*)(scl + BB * 16);         // 64 counters, 64B stride

  hipMemsetAsync(cnt, 0, BB * 16 * sizeof(int), stream);  // reset per iter
  probs_kernel<<<(BB * SS) / 16, 256, 0, stream>>>(text, emb, W, bias, out_probs);
  seg_kernel<<<BB * 4, 256, 0, stream>>>(text, tags, trans, out_probs, gm, scl,
                                         cnt, out_lens, out_ll);
}

// Round 6
// 137.402 us; speedup vs baseline: 1.1417x; 1.1417x over previous
//
#include <hip/hip_runtime.h>
#include <hip/hip_bf16.h>

// Problem constants
#define VOCAB 50000
#define ED    300
#define NT    16
#define BB    64
#define SS    512

#define LOG2E 1.4426950408889634f
#define LN2   0.6931471805599453f
#define WSTR  308   // padded W-transpose stride (2-way bank aliasing = free)

// ---------------------------------------------------------------------------
// Kernel 1: probs[row,:] = emb[text[row]] @ W + bias.  (verified, unchanged)
// ---------------------------------------------------------------------------
__global__ __launch_bounds__(256) void probs_kernel(const int* __restrict__ text,
                                                    const float* __restrict__ emb,
                                                    const float* __restrict__ W,
                                                    const float* __restrict__ bias,
                                                    float* __restrict__ out_probs) {
  __shared__ float wt[NT * WSTR];  // wt[t*WSTR + d] = W[d*16 + t]

  const int tid = threadIdx.x;
  const int lane = tid & 63, wave = tid >> 6;
  const int r = lane >> 4, t = lane & 15;
  const int row = blockIdx.x * 16 + wave * 4 + r;

  for (int e = tid; e < ED * NT; e += 256) {
    int d = e >> 4, tt = e & 15;
    wt[tt * WSTR + d] = W[e];
  }

  const int tok = text[row];
  const float4* erow = (const float4*)(emb + (size_t)tok * ED);
  float acc = bias[t];

  float4 A[8];
#pragma unroll
  for (int i = 0; i < 8; ++i) A[i] = erow[i];

  __syncthreads();

  const float4* w4 = (const float4*)(wt + t * WSTR);
#pragma unroll
  for (int c = 0; c < 75; ++c) {
    float4 e = A[c & 7];
    if (c < 67) A[c & 7] = erow[c + 8];
    float4 w = w4[c];
    acc = fmaf(e.x, w.x, acc);
    acc = fmaf(e.y, w.y, acc);
    acc = fmaf(e.z, w.z, acc);
    acc = fmaf(e.w, w.w, acc);
  }
  out_probs[(size_t)row * NT + t] = acc;
}

// ---------------------------------------------------------------------------
// DPP helpers (controls HW-verified).
// ---------------------------------------------------------------------------
template <int CTRL>
__device__ __forceinline__ float dppmov(float x) {
  int xi = __float_as_int(x);
  return __int_as_float(
      __builtin_amdgcn_update_dpp(xi, xi, CTRL, 0xF, 0xF, false));
}

// 16-lane max reduce (verified pattern)
__device__ __forceinline__ float max16(float x) {
  x = fmaxf(x, dppmov<0xB1>(x));
  x = fmaxf(x, dppmov<0x4E>(x));
  x = fmaxf(x, dppmov<0x141>(x));
  x = fmaxf(x, dppmov<0x140>(x));
  return x;
}

// ---------------------------------------------------------------------------
// One CRF step / matvec, fused DPP (HW-verified).
//   gn_j = (sum_m g_{j^m} * E[m]_j) * pe_j
// With per-lane-group data, each 16-lane group computes an independent matvec.
// ---------------------------------------------------------------------------
__device__ __forceinline__ float crf_step(float g, float pe, const float E[16]) {
  float gn, h, m, c, a1, a2, a3;
  asm("s_nop 1\n\t"
      "v_mov_b32_dpp %[h], %[g] row_half_mirror row_mask:0xf bank_mask:0xf\n\t"
      "v_mov_b32_dpp %[m], %[g] row_mirror row_mask:0xf bank_mask:0xf\n\t"
      "v_mul_f32 %[gn], %[g], %[e0]\n\t"
      "v_fmac_f32_dpp %[gn], %[g], %[e1] quad_perm:[1,0,3,2] row_mask:0xf bank_mask:0xf\n\t"
      "v_fmac_f32_dpp %[gn], %[g], %[e2] quad_perm:[2,3,0,1] row_mask:0xf bank_mask:0xf\n\t"
      "v_fmac_f32_dpp %[gn], %[g], %[e3] quad_perm:[3,2,1,0] row_mask:0xf bank_mask:0xf\n\t"
      "v_mov_b32_dpp %[c], %[m] row_half_mirror row_mask:0xf bank_mask:0xf\n\t"
      "v_mul_f32 %[a1], %[h], %[e7]\n\t"
      "v_fmac_f32_dpp %[a1], %[h], %[e6] quad_perm:[1,0,3,2] row_mask:0xf bank_mask:0xf\n\t"
      "v_fmac_f32_dpp %[a1], %[h], %[e5] quad_perm:[2,3,0,1] row_mask:0xf bank_mask:0xf\n\t"
      "v_fmac_f32_dpp %[a1], %[h], %[e4] quad_perm:[3,2,1,0] row_mask:0xf bank_mask:0xf\n\t"
      "v_mul_f32 %[a2], %[m], %[e15]\n\t"
      "v_fmac_f32_dpp %[a2], %[m], %[e14] quad_perm:[1,0,3,2] row_mask:0xf bank_mask:0xf\n\t"
      "v_fmac_f32_dpp %[a2], %[m], %[e13] quad_perm:[2,3,0,1] row_mask:0xf bank_mask:0xf\n\t"
      "v_fmac_f32_dpp %[a2], %[m], %[e12] quad_perm:[3,2,1,0] row_mask:0xf bank_mask:0xf\n\t"
      "v_mul_f32 %[a3], %[c], %[e8]\n\t"
      "v_fmac_f32_dpp %[a3], %[c], %[e9] quad_perm:[1,0,3,2] row_mask:0xf bank_mask:0xf\n\t"
      "v_fmac_f32_dpp %[a3], %[c], %[e10] quad_perm:[2,3,0,1] row_mask:0xf bank_mask:0xf\n\t"
      "v_fmac_f32_dpp %[a3], %[c], %[e11] quad_perm:[3,2,1,0] row_mask:0xf bank_mask:0xf\n\t"
      "v_add_f32 %[gn], %[gn], %[a1]\n\t"
      "v_add_f32 %[a2], %[a2], %[a3]\n\t"
      "v_add_f32 %[gn], %[gn], %[a2]\n\t"
      "v_mul_f32 %[gn], %[gn], %[pe]"
      : [gn] "=&v"(gn), [h] "=&v"(h), [m] "=&v"(m), [c] "=&v"(c),
        [a1] "=&v"(a1), [a2] "=&v"(a2), [a3] "=&v"(a3)
      : [g] "v"(g), [pe] "v"(pe),
        [e0] "v"(E[0]), [e1] "v"(E[1]), [e2] "v"(E[2]), [e3] "v"(E[3]),
        [e4] "v"(E[4]), [e5] "v"(E[5]), [e6] "v"(E[6]), [e7] "v"(E[7]),
        [e8] "v"(E[8]), [e9] "v"(E[9]), [e10] "v"(E[10]), [e11] "v"(E[11]),
        [e12] "v"(E[12]), [e13] "v"(E[13]), [e14] "v"(E[14]), [e15] "v"(E[15]));
  return gn;
}

// ---------------------------------------------------------------------------
// Phase A: per-segment 16x16 transfer-matrix products.
// Grid: 64 batches x 4 blocks, 256 threads (4 waves). Wave w of block-quarter
// q4 owns segment seg = q4*4 + w: steps s in [1+32*seg, 1+32*seg+segsz),
// segsz = 31 for seg 15 else 32. Active steps = prefix with s < len; the
// rest leave the unit-column init -> exact identity matrix.
// Lane-group g parallelism: group q, reg r holds column c = 4q+r of P.
// Output (d_ws): gm[(b*16+seg)*256 + m*16 + j] = P[j][j^m]  (xor layout,
// directly consumable by crf_step in phase B), scl[b*16+seg] = log2(max P).
// ---------------------------------------------------------------------------
__global__ __launch_bounds__(256) void seg_kernel(const int* __restrict__ text,
                                                  const float* __restrict__ trans,
                                                  const float* __restrict__ probs,
                                                  float* __restrict__ gm,
                                                  float* __restrict__ scl) {
  __shared__ float pe_lds[128 * 16];   // pe for this block's 128 rows
  __shared__ float xsc[4][16 * 17];    // per-wave transpose scratch (padded)

  const int tid = threadIdx.x;
  const int lane = tid & 63;
  const int w = tid >> 6;        // wave 0..3
  const int q = lane >> 4;       // lane group 0..3
  const int j = lane & 15;       // row index
  const int b = blockIdx.x >> 2;
  const int q4 = blockIdx.x & 3;
  const int seg = q4 * 4 + w;    // 0..15
  const int s_start = 1 + 32 * seg;
  const int segsz = (seg == 15) ? 31 : 32;

  // ---- stage pe = exp(probs) for rows [1+128*q4, 1+128*q4+128) ----
  {
    const float4* src = (const float4*)(probs + (size_t)b * SS * NT + (1 + 128 * q4) * NT);
    float4* dst = (float4*)pe_lds;
#pragma unroll
    for (int i = 0; i < 2; ++i) {
      float4 v = src[tid + 256 * i];
      v.x = exp2f(v.x * LOG2E);
      v.y = exp2f(v.y * LOG2E);
      v.z = exp2f(v.z * LOG2E);
      v.w = exp2f(v.w * LOG2E);
      dst[tid + 256 * i] = v;
    }
  }

  // ---- len (per-wave, verified pattern; redundant across waves) ----
  const int* tx = text + b * SS;
  int cz = 0;
#pragma unroll
  for (int k = 0; k < 8; ++k) cz += (tx[lane + 64 * k] != 0) ? 1 : 0;
  for (int off = 32; off > 0; off >>= 1) cz += __shfl_xor(cz, off, 64);
  const int len = cz;

  // ---- E[k] = exp(trans[j^k, j]) * 2^-5 ----
  float E[16];
#pragma unroll
  for (int k = 0; k < 16; ++k) E[k] = __expf(trans[((j ^ k) << 4) + j]) * 0.03125f;

  __syncthreads();  // pe_lds ready

  // ---- unit-column init: column c = 4q + r ----
  float g0 = (j == 4 * q + 0) ? 1.f : 0.f;
  float g1 = (j == 4 * q + 1) ? 1.f : 0.f;
  float g2 = (j == 4 * q + 2) ? 1.f : 0.f;
  float g3 = (j == 4 * q + 3) ? 1.f : 0.f;

  // ---- segment product: na active steps (prefix property: active iff s<len)
  int na = len - s_start;
  na = (na < 0) ? 0 : ((na > segsz) ? segsz : na);

  const int row0 = 32 * w;
  for (int it = 0; it < na; ++it) {
    float pe = pe_lds[(row0 + it) * NT + j];
    g0 = crf_step(g0, pe, E);
    g1 = crf_step(g1, pe, E);
    g2 = crf_step(g2, pe, E);
    g3 = crf_step(g3, pe, E);
  }

  // ---- renorm matrix to max 1 (exact fold via scl) ----
  float mx = fmaxf(fmaxf(g0, g1), fmaxf(g2, g3));
  mx = max16(mx);
  mx = fmaxf(mx, __shfl_xor(mx, 16, 64));
  mx = fmaxf(mx, __shfl_xor(mx, 32, 64));
  float rr = 1.0f / mx;
  g0 *= rr; g1 *= rr; g2 *= rr; g3 *= rr;

  // ---- transpose to xor layout via per-wave LDS scratch ----
  float* xs = xsc[w];
  xs[(4 * q + 0) * 17 + j] = g0;   // xs[c*17 + row] = P[row][c]
  xs[(4 * q + 1) * 17 + j] = g1;
  xs[(4 * q + 2) * 17 + j] = g2;
  xs[(4 * q + 3) * 17 + j] = g3;
  // same-wave LDS write->read: lgkmcnt-ordered, no barrier needed
  float* outm = gm + ((size_t)(b * 16 + seg)) * 256;
#pragma unroll
  for (int r = 0; r < 4; ++r) {
    const int m = 4 * q + r;                 // group q emits m = 4q..4q+3
    outm[m * 16 + j] = xs[(j ^ m) * 17 + j]; // = P[j][j^m]
  }
  if (lane == 0) scl[b * 16 + seg] = __log2f(mx);
}

// ---------------------------------------------------------------------------
// Phase B: lens + scores + 15-matvec combine + logsumexp. 64 blocks x 64 thr.
// ---------------------------------------------------------------------------
__global__ __launch_bounds__(64) void crf2_kernel(const int* __restrict__ text,
                                                  const int* __restrict__ tags,
                                                  const float* __restrict__ trans,
                                                  const float* __restrict__ probs,
                                                  const float* __restrict__ gm,
                                                  const float* __restrict__ scl,
                                                  float* __restrict__ out_lens,
                                                  float* __restrict__ out_ll) {
  const int tid = threadIdx.x;
  const int j = tid & 15;
  const int b = blockIdx.x;

  // ---- lens ----
  const int* tx = text + b * SS;
  int cz = 0;
#pragma unroll
  for (int k = 0; k < 8; ++k) cz += (tx[tid + 64 * k] != 0) ? 1 : 0;
  for (int off = 32; off > 0; off >>= 1) cz += __shfl_xor(cz, off, 64);
  const int len = cz;
  if (tid == 0) out_lens[b] = (float)len;

  // ---- tags + binary score ----
  const int* tg = tags + b * SS;
  int tgv[8];
  float sb = 0.f;
#pragma unroll
  for (int it = 0; it < 8; ++it) {
    const int s = tid + 64 * it;
    tgv[it] = tg[s];
    if (s >= 1 && s < len) sb += trans[tg[s - 1] * 16 + tgv[it]];
  }

  const float* pb = probs + (size_t)b * SS * NT;
  const float* gb = gm + (size_t)b * 16 * 256;

  // ---- segment scales ----
  float K2 = 0.f;
#pragma unroll
  for (int k = 0; k < 16; ++k) K2 += scl[b * 16 + k];

  // ---- alpha0, then 16 matvecs (double-buffered coalesced loads) ----
  float g = exp2f(pb[j] * LOG2E);

  float EA[16], EB[16];
#pragma unroll
  for (int m = 0; m < 16; ++m) EA[m] = gb[m * 16 + j];

  for (int k = 0; k < 16; k += 2) {
#pragma unroll
    for (int m = 0; m < 16; ++m) EB[m] = gb[(k + 1) * 256 + m * 16 + j];
    g = crf_step(g, 1.0f, EA);
    {
      float mx = max16(g);
      float rr = 1.0f / mx;
      K2 -= __log2f(rr);
      g *= rr;
    }
    if (k < 14) {
#pragma unroll
      for (int m = 0; m < 16; ++m) EA[m] = gb[(k + 2) * 256 + m * 16 + j];
    }
    g = crf_step(g, 1.0f, EB);
    {
      float mx = max16(g);
      float rr = 1.0f / mx;
      K2 -= __log2f(rr);
      g *= rr;
    }
  }

  // ---- unary score ----
  float su = 0.f;
#pragma unroll
  for (int it = 0; it < 8; ++it) {
    const int s = tid + 64 * it;
    if (s < len) su += pb[s * NT + tgv[it]];
  }
  float sc = su + sb;
  for (int off = 32; off > 0; off >>= 1) sc += __shfl_xor(sc, off, 64);

  // ---- final logsumexp; +5*T undoes the per-active-step 2^-5 scaling ----
  const int T = (len > 0) ? len - 1 : 0;
  float x = g;
  x += dppmov<0xB1>(x);
  x += dppmov<0x4E>(x);
  x += dppmov<0x141>(x);
  x += dppmov<0x140>(x);
  float log_norm = LN2 * (K2 + 5.0f * (float)T + __log2f(x));
  if (tid == 0) out_ll[b] = sc - log_norm;
}

// ---------------------------------------------------------------------------
extern "C" void kernel_launch(void* const* d_in, const int* in_sizes, int n_in,
                              void* d_out, int out_size, void* d_ws, size_t ws_size,
                              hipStream_t stream) {
  const int* text = (const int*)d_in[0];
  const int* tags = (const int*)d_in[1];
  const float* emb = (const float*)d_in[2];
  const float* W = (const float*)d_in[3];
  const float* bias = (const float*)d_in[4];
  const float* trans = (const float*)d_in[5];

  float* out = (float*)d_out;
  float* out_probs = out;                   // 64*512*16
  float* out_lens = out + BB * SS * NT;     // 64
  float* out_ll = out + BB * SS * NT + BB;  // 64

  float* gm = (float*)d_ws;                 // 64*16*256 floats = 1 MB
  float* scl = gm + BB * 16 * 256;          // 64*16 floats

  probs_kernel<<<(BB * SS) / 16, 256, 0, stream>>>(text, emb, W, bias, out_probs);
  seg_kernel<<<BB * 4, 256, 0, stream>>>(text, trans, out_probs, gm, scl);
  crf2_kernel<<<BB, 64, 0, stream>>>(text, tags, trans, out_probs, gm, scl,
                                     out_lens, out_ll);
}